// Round 3
// baseline (480.061 us; speedup 1.0000x reference)
//
#include <hip/hip_runtime.h>

// Problem constants (B=1)
#define SS 2048
#define DD 2048
#define HH 16
#define DHD 128

// scores scale: reference divides by sqrt(DH) with DH=128
// (setup_inputs' 1/sqrt(D) is the WEIGHT-INIT scale, not the attention scale)
#define SCORE_SCALE 0.08838834764831845f

typedef unsigned short u16;
typedef __attribute__((ext_vector_type(8))) short short8;
typedef __attribute__((ext_vector_type(4))) short short4v;
typedef __attribute__((ext_vector_type(4))) float f32x4;

__device__ __forceinline__ float bf2f(u16 v) {
  union { unsigned u; float f; } x; x.u = ((unsigned)v) << 16; return x.f;
}
__device__ __forceinline__ u16 f2bf(float f) {
  union { float f; unsigned u; } x; x.f = f;
  unsigned r = (x.u + 0x7fffu + ((x.u >> 16) & 1u)) >> 16;  // RTNE
  return (u16)r;
}

// async global->LDS, 16B per lane; LDS dest must be wave-uniform base (lane*16 auto)
#define GL2LDS16(g, l) __builtin_amdgcn_global_load_lds( \
    (const __attribute__((address_space(1))) void*)(g),   \
    (__attribute__((address_space(3))) void*)(l), 16, 0, 0)

// ---------------- f32 -> bf16 convert (vectorized) ----------------
__global__ __launch_bounds__(256) void cvt_bf16(const float* __restrict__ in,
                                                u16* __restrict__ out) {
  int i = (blockIdx.x * 256 + threadIdx.x) * 8;
  float4 a = *(const float4*)(in + i);
  float4 b = *(const float4*)(in + i + 4);
  short8 o;
  o[0] = (short)f2bf(a.x); o[1] = (short)f2bf(a.y);
  o[2] = (short)f2bf(a.z); o[3] = (short)f2bf(a.w);
  o[4] = (short)f2bf(b.x); o[5] = (short)f2bf(b.y);
  o[6] = (short)f2bf(b.z); o[7] = (short)f2bf(b.w);
  *(short8*)(out + i) = o;
}

// ---------------- GEMM: C[M][N] = A[M][K] * B[N][K]^T (bf16 in, f32 acc) -----
// 128x128 tile, BK=32, 4 waves (2x2 of 64x64), mfma_f32_16x16x32_bf16.
// TR=true: store C transposed as CT[N][M] (vectorized 4-row bf16 stores).
template<typename OUT, bool TR>
__global__ __launch_bounds__(256) void gemm_bt(const u16* __restrict__ A,
                                               const u16* __restrict__ B,
                                               OUT* __restrict__ C,
                                               int M, int N, int K) {
  __shared__ u16 As[128 * 32];
  __shared__ u16 Bs[128 * 32];
  const int tid = threadIdx.x;
  const int wave = tid >> 6, lane = tid & 63;
  const int wm = (wave >> 1) * 64, wn = (wave & 1) * 64;
  const int bm = blockIdx.y * 128, bn = blockIdx.x * 128;
  const int lrow = lane >> 2, lcol = (lane & 3) * 8;   // staging: 4 lanes/row
  const int fr = lane & 15, fq8 = (lane >> 4) * 8, fq4 = (lane >> 4) * 4;
  f32x4 acc[4][4] = {};
  for (int k0 = 0; k0 < K; k0 += 32) {
#pragma unroll
    for (int half = 0; half < 2; ++half) {
      const int rb = half * 64 + wave * 16;  // wave-uniform row base
      GL2LDS16(A + (size_t)(bm + rb + lrow) * K + k0 + lcol, As + rb * 32);
      GL2LDS16(B + (size_t)(bn + rb + lrow) * K + k0 + lcol, Bs + rb * 32);
    }
    __syncthreads();
    short8 af[4], bb[4];
#pragma unroll
    for (int m = 0; m < 4; ++m)
      af[m] = *(const short8*)(As + (wm + m * 16 + fr) * 32 + fq8);
#pragma unroll
    for (int n = 0; n < 4; ++n)
      bb[n] = *(const short8*)(Bs + (wn + n * 16 + fr) * 32 + fq8);
#pragma unroll
    for (int m = 0; m < 4; ++m)
#pragma unroll
      for (int n = 0; n < 4; ++n)
        acc[m][n] = __builtin_amdgcn_mfma_f32_16x16x32_bf16(af[m], bb[n], acc[m][n], 0, 0, 0);
    __syncthreads();
  }
  // epilogue: C/D layout col=lane&15, row=(lane>>4)*4+reg  (m89-verified)
#pragma unroll
  for (int m = 0; m < 4; ++m) {
#pragma unroll
    for (int n = 0; n < 4; ++n) {
      const int row0 = bm + wm + m * 16 + fq4;
      const int col  = bn + wn + n * 16 + fr;
      if constexpr (TR) {
        short4v t;
#pragma unroll
        for (int r = 0; r < 4; ++r) t[r] = (short)f2bf(acc[m][n][r]);
        *(short4v*)((u16*)C + (size_t)col * M + row0) = t;
      } else {
#pragma unroll
        for (int r = 0; r < 4; ++r) {
          float v = acc[m][n][r];
          if constexpr (sizeof(OUT) == 2)
            ((u16*)C)[(size_t)(row0 + r) * N + col] = f2bf(v);
          else
            ((float*)C)[(size_t)(row0 + r) * N + col] = v;
        }
      }
    }
  }
}

// ---------------- RoPE: q/k [S][H*DH] bf16 -> [H][S][DH] bf16 ----------------
__global__ __launch_bounds__(128) void rope_qk(const u16* __restrict__ qin,
                                               const u16* __restrict__ kin,
                                               const float* __restrict__ cosd,
                                               const float* __restrict__ sind,
                                               u16* __restrict__ qt,
                                               u16* __restrict__ kt) {
  const int s = blockIdx.x, h = blockIdx.y, d = threadIdx.x;
  const float c = cosd[s * DHD + d], sn = sind[s * DHD + d];
  const int base = s * DD + h * DHD;
  const float q0 = bf2f(qin[base + d]);
  const float k0 = bf2f(kin[base + d]);
  const float qr = (d < 64) ? -bf2f(qin[base + d + 64]) : bf2f(qin[base + d - 64]);
  const float kr = (d < 64) ? -bf2f(kin[base + d + 64]) : bf2f(kin[base + d - 64]);
  const size_t o = ((size_t)h * SS + s) * DHD + d;
  qt[o] = f2bf(q0 * c + qr * sn);
  kt[o] = f2bf(k0 * c + kr * sn);
}

// ---------------- Flash attention (causal, tanh soft-cap 50) -----------------
// grid (S/64, H), 256 threads = 4 waves; wave w owns q rows qb*64+w*16 .. +15.
// qt,kt: [H][S][DH] bf16 ; vt: [H*DH][S] bf16 (V transposed) ; ao: [S][H*DH]
__global__ __launch_bounds__(256) void attn_fwd(const u16* __restrict__ qt,
                                                const u16* __restrict__ kt,
                                                const u16* __restrict__ vt,
                                                u16* __restrict__ ao) {
  __shared__ u16 Ks[64 * 128];   // [k][d]
  __shared__ u16 Vs[128 * 64];   // [d][k]  (V^T tile)
  __shared__ u16 Ps[4][16 * 64]; // per-wave P relayout buffer
  const int qb = blockIdx.x, h = blockIdx.y;
  const int tid = threadIdx.x, wave = tid >> 6, lane = tid & 63;
  const int q0 = qb * 64 + wave * 16;
  const int fr = lane & 15, fq8 = (lane >> 4) * 8, fq4 = (lane >> 4) * 4;

  short8 qf[4];
#pragma unroll
  for (int c = 0; c < 4; ++c)
    qf[c] = *(const short8*)(qt + ((size_t)h * SS + q0 + fr) * DHD + c * 32 + fq8);

  f32x4 oacc[8] = {};
  float mrun[4], lrun[4];
#pragma unroll
  for (int r = 0; r < 4; ++r) { mrun[r] = -1e30f; lrun[r] = 0.f; }

  const int nt = qb + 1;
  for (int t = 0; t < nt; ++t) {
    const int kb = t * 64;
    // stage K tile [64][128]
#pragma unroll
    for (int i = 0; i < 4; ++i) {
      const int brow = i * 16 + wave * 4;  // wave-uniform
      GL2LDS16(kt + ((size_t)h * SS + kb + brow + (lane >> 4)) * DHD + (lane & 15) * 8,
               Ks + brow * 128);
    }
    // stage V^T tile [128][64]
#pragma unroll
    for (int i = 0; i < 4; ++i) {
      const int brow = i * 32 + wave * 8;  // wave-uniform
      GL2LDS16(vt + ((size_t)h * DHD + brow + (lane >> 3)) * SS + kb + (lane & 7) * 8,
               Vs + brow * 64);
    }
    __syncthreads();

    // S = Q K^T
    f32x4 sacc[4] = {};
#pragma unroll
    for (int n = 0; n < 4; ++n)
#pragma unroll
      for (int c = 0; c < 4; ++c) {
        short8 b = *(const short8*)(Ks + (n * 16 + fr) * 128 + c * 32 + fq8);
        sacc[n] = __builtin_amdgcn_mfma_f32_16x16x32_bf16(qf[c], b, sacc[n], 0, 0, 0);
      }

    // soft-cap + causal mask + row max
    const bool diag = (t == nt - 1);
    float p[4][4], tmax[4];
#pragma unroll
    for (int r = 0; r < 4; ++r) tmax[r] = -1e30f;
#pragma unroll
    for (int n = 0; n < 4; ++n)
#pragma unroll
      for (int r = 0; r < 4; ++r) {
        float sv = 50.0f * tanhf(sacc[n][r] * (SCORE_SCALE / 50.0f));
        if (diag) {
          const int kg = kb + n * 16 + fr;
          const int qg = q0 + fq4 + r;
          if (kg > qg) sv = -1e9f;
        }
        p[n][r] = sv;
        tmax[r] = fmaxf(tmax[r], sv);
      }
#pragma unroll
    for (int r = 0; r < 4; ++r) {
      float v = tmax[r];
      v = fmaxf(v, __shfl_xor(v, 1));
      v = fmaxf(v, __shfl_xor(v, 2));
      v = fmaxf(v, __shfl_xor(v, 4));
      v = fmaxf(v, __shfl_xor(v, 8));
      tmax[r] = v;
    }
    float alpha[4], rsum[4];
#pragma unroll
    for (int r = 0; r < 4; ++r) {
      const float mnew = fmaxf(mrun[r], tmax[r]);
      alpha[r] = __expf(mrun[r] - mnew);
      mrun[r] = mnew;
      rsum[r] = 0.f;
    }
#pragma unroll
    for (int n = 0; n < 4; ++n)
#pragma unroll
      for (int r = 0; r < 4; ++r) {
        const float e = __expf(p[n][r] - mrun[r]);
        p[n][r] = e;
        rsum[r] += e;
      }
#pragma unroll
    for (int r = 0; r < 4; ++r) {
      float v = rsum[r];
      v += __shfl_xor(v, 1); v += __shfl_xor(v, 2);
      v += __shfl_xor(v, 4); v += __shfl_xor(v, 8);
      lrun[r] = lrun[r] * alpha[r] + v;
    }
#pragma unroll
    for (int n = 0; n < 8; ++n)
#pragma unroll
      for (int r = 0; r < 4; ++r) oacc[n][r] *= alpha[r];

    // P (C-layout) -> LDS -> A-fragment layout
    u16* ps = &Ps[wave][0];
#pragma unroll
    for (int n = 0; n < 4; ++n)
#pragma unroll
      for (int r = 0; r < 4; ++r)
        ps[(fq4 + r) * 64 + n * 16 + fr] = f2bf(p[n][r]);
    short8 pa[2];
#pragma unroll
    for (int kc = 0; kc < 2; ++kc)
      pa[kc] = *(const short8*)(ps + fr * 64 + kc * 32 + fq8);

    // O += P V
#pragma unroll
    for (int kc = 0; kc < 2; ++kc)
#pragma unroll
      for (int n = 0; n < 8; ++n) {
        short8 b = *(const short8*)(Vs + (n * 16 + fr) * 64 + kc * 32 + fq8);
        oacc[n] = __builtin_amdgcn_mfma_f32_16x16x32_bf16(pa[kc], b, oacc[n], 0, 0, 0);
      }
    __syncthreads();
  }

  // normalize + store [S][H*DH]
  float rl[4];
#pragma unroll
  for (int r = 0; r < 4; ++r) rl[r] = 1.0f / lrun[r];
#pragma unroll
  for (int n = 0; n < 8; ++n)
#pragma unroll
    for (int r = 0; r < 4; ++r) {
      const float v = oacc[n][r] * rl[r];
      ao[(size_t)(q0 + fq4 + r) * DD + h * DHD + n * 16 + fr] = f2bf(v);
    }
}

// ---------------- launch ----------------
extern "C" void kernel_launch(void* const* d_in, const int* in_sizes, int n_in,
                              void* d_out, int out_size, void* d_ws, size_t ws_size,
                              hipStream_t stream) {
  const float* x        = (const float*)d_in[0];
  const float* rope_cos = (const float*)d_in[1];
  const float* rope_sin = (const float*)d_in[2];
  // d_in[3] = mask: deterministic causal, handled inline
  const float* wq = (const float*)d_in[4];
  const float* wk = (const float*)d_in[5];
  const float* wv = (const float*)d_in[6];
  const float* wo = (const float*)d_in[7];
  float* out = (float*)d_out;

  // Workspace reuse plan (7 x 8MB = 56MB). Kernels are sequential on one
  // stream, so a buffer may be reused once its last reader has launched.
  u16* ws = (u16*)d_ws;
  const size_t SZ = (size_t)SS * DD;  // 4M elems, 8MB bf16
  u16* xb  = ws + 0 * SZ;             // x bf16        (live: cvt .. V-gemm)
  u16* wqb = ws + 1 * SZ;             // wq bf16       -> reused as qt
  u16* wkb = ws + 2 * SZ;             // wk bf16       -> reused as kt
  u16* wvb = ws + 3 * SZ;             // wv bf16       -> reused as ao
  u16* q_  = ws + 4 * SZ;             // pre-rope Q    -> reused as wob
  u16* k_  = ws + 5 * SZ;             // pre-rope K
  u16* vt  = ws + 6 * SZ;             // V^T [H*DH][S]
  u16* qt  = wqb;                     // [H][S][DH]
  u16* kt  = wkb;
  u16* ao  = wvb;                     // attention out [S][H*DH]
  u16* wob = q_;

  const int cvtGrid = (int)(SZ / (256 * 8));
  cvt_bf16<<<cvtGrid, 256, 0, stream>>>(x,  xb);
  cvt_bf16<<<cvtGrid, 256, 0, stream>>>(wq, wqb);
  cvt_bf16<<<cvtGrid, 256, 0, stream>>>(wk, wkb);
  cvt_bf16<<<cvtGrid, 256, 0, stream>>>(wv, wvb);

  dim3 g16(16, 16);
  gemm_bt<u16, false><<<g16, 256, 0, stream>>>(xb, wqb, q_, SS, DD, DD);
  gemm_bt<u16, false><<<g16, 256, 0, stream>>>(xb, wkb, k_, SS, DD, DD);
  gemm_bt<u16, true ><<<g16, 256, 0, stream>>>(xb, wvb, vt, SS, DD, DD);  // -> V^T

  rope_qk<<<dim3(SS, HH), 128, 0, stream>>>(q_, k_, rope_cos, rope_sin, qt, kt);

  cvt_bf16<<<cvtGrid, 256, 0, stream>>>(wo, wob);  // q_ dead after rope

  attn_fwd<<<dim3(SS / 64, HH), 256, 0, stream>>>(qt, kt, vt, ao);

  gemm_bt<float, false><<<g16, 256, 0, stream>>>(ao, wob, out, SS, DD, DD);
}

// Round 4
// 363.202 us; speedup vs baseline: 1.3217x; 1.3217x over previous
//
#include <hip/hip_runtime.h>

// Problem constants (B=1)
#define SS 2048
#define DD 2048
#define HH 16
#define DHD 128

// scores scale: reference divides by sqrt(DH) with DH=128
#define SCORE_SCALE 0.08838834764831845f

typedef unsigned short u16;
typedef __attribute__((ext_vector_type(8))) short short8;
typedef __attribute__((ext_vector_type(4))) short short4v;
typedef __attribute__((ext_vector_type(4))) float f32x4;

__device__ __forceinline__ float bf2f(u16 v) {
  union { unsigned u; float f; } x; x.u = ((unsigned)v) << 16; return x.f;
}
__device__ __forceinline__ u16 f2bf(float f) {
  union { float f; unsigned u; } x; x.f = f;
  unsigned r = (x.u + 0x7fffu + ((x.u >> 16) & 1u)) >> 16;  // RTNE
  return (u16)r;
}
// fast tanh: sign(u)*(1-e^{-2|u|})/(1+e^{-2|u|})  (no overflow; 1 v_exp + 1 v_rcp)
__device__ __forceinline__ float fast_tanh(float u) {
  const float e = __expf(-2.0f * fabsf(u));
  return copysignf((1.0f - e) / (1.0f + e), u);
}

// async global->LDS, 16B per lane; LDS dest = wave-uniform base + lane*16
#define GL2LDS16(g, l) __builtin_amdgcn_global_load_lds( \
    (const __attribute__((address_space(1))) void*)(g),   \
    (__attribute__((address_space(3))) void*)(l), 16, 0, 0)

// ---------------- f32 -> bf16 convert (vectorized) ----------------
__global__ __launch_bounds__(256) void cvt_bf16(const float* __restrict__ in,
                                                u16* __restrict__ out) {
  int i = (blockIdx.x * 256 + threadIdx.x) * 8;
  float4 a = *(const float4*)(in + i);
  float4 b = *(const float4*)(in + i + 4);
  short8 o;
  o[0] = (short)f2bf(a.x); o[1] = (short)f2bf(a.y);
  o[2] = (short)f2bf(a.z); o[3] = (short)f2bf(a.w);
  o[4] = (short)f2bf(b.x); o[5] = (short)f2bf(b.y);
  o[6] = (short)f2bf(b.z); o[7] = (short)f2bf(b.w);
  *(short8*)(out + i) = o;
}

// ============ shared GEMM K-loop pieces (128x128 tile, BK=32, 2-phase) =======
// LDS tile swizzle: element (row, chunk c of 8 elems) stored at
//   row*32 + (c ^ (row&3))*8   -- spreads frag reads across all 32 banks.
// Staging keeps LDS dest LINEAR (gl2lds requirement) and pre-swizzles the
// GLOBAL source chunk instead (rule: both-sides-or-neither, m173 pattern).

#define GEMM_STAGE(Asrc, Bsrc, Adst, Bdst, kofs)                               \
  _Pragma("unroll")                                                            \
  for (int half = 0; half < 2; ++half) {                                       \
    const int rb = half * 64 + wave * 16;                                      \
    GL2LDS16(Asrc + (size_t)(bm + rb + lrow) * DD + (kofs) + c8s, Adst + rb * 32); \
    GL2LDS16(Bsrc + (size_t)(bn + rb + lrow) * DD + (kofs) + c8s, Bdst + rb * 32); \
  }

#define GEMM_COMPUTE(Abuf, Bbuf)                                               \
  {                                                                            \
    short8 af[4], bb[4];                                                       \
    _Pragma("unroll")                                                          \
    for (int m = 0; m < 4; ++m) {                                              \
      const int row = wm + m * 16 + fr;                                        \
      af[m] = *(const short8*)(Abuf + row * 32 + (hi ^ (row & 3)) * 8);        \
    }                                                                          \
    _Pragma("unroll")                                                          \
    for (int n = 0; n < 4; ++n) {                                              \
      const int row = wn + n * 16 + fr;                                        \
      bb[n] = *(const short8*)(Bbuf + row * 32 + (hi ^ (row & 3)) * 8);        \
    }                                                                          \
    _Pragma("unroll")                                                          \
    for (int m = 0; m < 4; ++m)                                                \
      _Pragma("unroll")                                                        \
      for (int n = 0; n < 4; ++n)                                              \
        acc[m][n] = __builtin_amdgcn_mfma_f32_16x16x32_bf16(af[m], bb[n], acc[m][n], 0, 0, 0); \
  }

// ---------------- GEMM: C[M][N] = A[M][K] * B[N][K]^T ------------------------
template<typename OUT, bool TR>
__global__ __launch_bounds__(256) void gemm_bt(const u16* __restrict__ A,
                                               const u16* __restrict__ B,
                                               OUT* __restrict__ C) {
  __shared__ u16 As[2][128 * 32];
  __shared__ u16 Bs[2][128 * 32];
  const int tid = threadIdx.x, wave = tid >> 6, lane = tid & 63;
  const int wm = (wave >> 1) * 64, wn = (wave & 1) * 64;
  const int bm = blockIdx.y * 128, bn = blockIdx.x * 128;
  const int lrow = lane >> 2;
  const int c8s = ((lane & 3) ^ (lrow & 3)) * 8;  // pre-swizzled global chunk
  const int fr = lane & 15, hi = lane >> 4, fq4 = hi * 4;
  f32x4 acc[4][4] = {};
  GEMM_STAGE(A, B, As[0], Bs[0], 0)
  __syncthreads();
  for (int kt = 0; kt < DD / 32; ++kt) {
    const int buf = kt & 1;
    if (kt + 1 < DD / 32) { GEMM_STAGE(A, B, As[buf ^ 1], Bs[buf ^ 1], (kt + 1) * 32) }
    GEMM_COMPUTE(As[buf], Bs[buf])
    __syncthreads();
  }
#pragma unroll
  for (int m = 0; m < 4; ++m)
#pragma unroll
    for (int n = 0; n < 4; ++n) {
      const int row0 = bm + wm + m * 16 + fq4;
      const int col  = bn + wn + n * 16 + fr;
      if constexpr (TR) {
        short4v t;
#pragma unroll
        for (int r = 0; r < 4; ++r) t[r] = (short)f2bf(acc[m][n][r]);
        *(short4v*)((u16*)C + (size_t)col * SS + row0) = t;
      } else {
#pragma unroll
        for (int r = 0; r < 4; ++r) {
          if constexpr (sizeof(OUT) == 2)
            ((u16*)C)[(size_t)(row0 + r) * DD + col] = f2bf(acc[m][n][r]);
          else
            ((float*)C)[(size_t)(row0 + r) * DD + col] = acc[m][n][r];
        }
      }
    }
}

// ---------------- z-batched QKV GEMM (z=0:Q, 1:K, 2:V-transposed) ------------
__global__ __launch_bounds__(256) void gemm_qkv(const u16* __restrict__ A,
                                                const u16* __restrict__ Bq,
                                                const u16* __restrict__ Bk,
                                                const u16* __restrict__ Bv,
                                                u16* __restrict__ Cq,
                                                u16* __restrict__ Ck,
                                                u16* __restrict__ Cvt) {
  __shared__ u16 As[2][128 * 32];
  __shared__ u16 Bs[2][128 * 32];
  const int z = blockIdx.z;
  const u16* B = (z == 0) ? Bq : (z == 1) ? Bk : Bv;
  const int tid = threadIdx.x, wave = tid >> 6, lane = tid & 63;
  const int wm = (wave >> 1) * 64, wn = (wave & 1) * 64;
  const int bm = blockIdx.y * 128, bn = blockIdx.x * 128;
  const int lrow = lane >> 2;
  const int c8s = ((lane & 3) ^ (lrow & 3)) * 8;
  const int fr = lane & 15, hi = lane >> 4, fq4 = hi * 4;
  f32x4 acc[4][4] = {};
  GEMM_STAGE(A, B, As[0], Bs[0], 0)
  __syncthreads();
  for (int kt = 0; kt < DD / 32; ++kt) {
    const int buf = kt & 1;
    if (kt + 1 < DD / 32) { GEMM_STAGE(A, B, As[buf ^ 1], Bs[buf ^ 1], (kt + 1) * 32) }
    GEMM_COMPUTE(As[buf], Bs[buf])
    __syncthreads();
  }
  u16* Cn = (z == 0) ? Cq : Ck;
#pragma unroll
  for (int m = 0; m < 4; ++m)
#pragma unroll
    for (int n = 0; n < 4; ++n) {
      const int row0 = bm + wm + m * 16 + fq4;
      const int col  = bn + wn + n * 16 + fr;
      if (z < 2) {
#pragma unroll
        for (int r = 0; r < 4; ++r)
          Cn[(size_t)(row0 + r) * DD + col] = f2bf(acc[m][n][r]);
      } else {
        short4v t;
#pragma unroll
        for (int r = 0; r < 4; ++r) t[r] = (short)f2bf(acc[m][n][r]);
        *(short4v*)(Cvt + (size_t)col * SS + row0) = t;
      }
    }
}

// ---------------- RoPE: q/k [S][H*DH] bf16 -> [H][S][DH] bf16 ----------------
__global__ __launch_bounds__(128) void rope_qk(const u16* __restrict__ qin,
                                               const u16* __restrict__ kin,
                                               const float* __restrict__ cosd,
                                               const float* __restrict__ sind,
                                               u16* __restrict__ qt,
                                               u16* __restrict__ kt) {
  const int s = blockIdx.x, h = blockIdx.y, d = threadIdx.x;
  const float c = cosd[s * DHD + d], sn = sind[s * DHD + d];
  const int base = s * DD + h * DHD;
  const float q0 = bf2f(qin[base + d]);
  const float k0 = bf2f(kin[base + d]);
  const float qr = (d < 64) ? -bf2f(qin[base + d + 64]) : bf2f(qin[base + d - 64]);
  const float kr = (d < 64) ? -bf2f(kin[base + d + 64]) : bf2f(kin[base + d - 64]);
  const size_t o = ((size_t)h * SS + s) * DHD + d;
  qt[o] = f2bf(q0 * c + qr * sn);
  kt[o] = f2bf(k0 * c + kr * sn);
}

// ---------------- Flash attention (causal, tanh soft-cap 50) -----------------
// 1-D grid 512 blocks; bid->(h,qb) mapped so each XCD keeps 2 heads' K/V in L2.
// 4 waves; wave w owns q rows qb*64+w*16..+15. Double-buffered K/V staging.
// LDS swizzle: K elem (r, chunk c) at r*128 + (c^(r&7))*8 ; V^T (r, chunk c)
// at r*64 + (c^(r&7))*8 ; staged via pre-swizzled GLOBAL source (linear dest).
__global__ __launch_bounds__(256) void attn_fwd(const u16* __restrict__ qt,
                                                const u16* __restrict__ kt,
                                                const u16* __restrict__ vt,
                                                u16* __restrict__ ao) {
  __shared__ u16 Ks[2][64 * 128];
  __shared__ u16 Vs[2][128 * 64];
  __shared__ u16 Ps[4][16 * 64];
  const int bid = blockIdx.x;
  const int h  = (bid & 7) + 8 * ((bid >> 3) & 1);
  const int qb = bid >> 4;
  const int tid = threadIdx.x, wave = tid >> 6, lane = tid & 63;
  const int q0 = qb * 64 + wave * 16;
  const int fr = lane & 15, hi = lane >> 4, fq8 = hi * 8, fq4 = hi * 4;

  // staging address components (computed once)
  const int kbrow0 = wave * 4 + (lane >> 4);      // + i*16 -> K row
  const int kc8    = (lane & 15);
  const int vbrow0 = wave * 8 + (lane >> 3);      // + i*32 -> V^T row
  const int vk8    = (lane & 7) ^ ((lane >> 3) & 7);

  short8 qf[4];
#pragma unroll
  for (int c = 0; c < 4; ++c)
    qf[c] = *(const short8*)(qt + ((size_t)h * SS + q0 + fr) * DHD + c * 32 + fq8);

  f32x4 oacc[8] = {};
  float mrun[4], lrun[4];
#pragma unroll
  for (int r = 0; r < 4; ++r) { mrun[r] = -1e30f; lrun[r] = 0.f; }

  const int nt = qb + 1;

  auto STAGE = [&](int t, int buf) {
    const int kb = t * 64;
#pragma unroll
    for (int i = 0; i < 4; ++i) {
      const int krow = i * 16 + kbrow0;
      const int c8 = kc8 ^ (krow & 7);
      GL2LDS16(kt + ((size_t)h * SS + kb + krow) * DHD + c8 * 8,
               &Ks[buf][(i * 16 + wave * 4) * 128]);
    }
#pragma unroll
    for (int i = 0; i < 4; ++i) {
      const int vrow = i * 32 + vbrow0;
      GL2LDS16(vt + ((size_t)h * DHD + vrow) * SS + kb + vk8 * 8,
               &Vs[buf][(i * 32 + wave * 8) * 64]);
    }
  };

  STAGE(0, 0);
  __syncthreads();

  for (int t = 0; t < nt; ++t) {
    const int buf = t & 1;
    if (t + 1 < nt) STAGE(t + 1, buf ^ 1);
    const int kb = t * 64;

    // S = Q K^T  (swizzled K reads: 8 bank-starts, 2-way = free)
    f32x4 sacc[4] = {};
#pragma unroll
    for (int n = 0; n < 4; ++n) {
      const int row = n * 16 + fr;
#pragma unroll
      for (int c = 0; c < 4; ++c) {
        short8 b = *(const short8*)(&Ks[buf][row * 128 + ((c * 4 + hi) ^ (fr & 7)) * 8]);
        sacc[n] = __builtin_amdgcn_mfma_f32_16x16x32_bf16(qf[c], b, sacc[n], 0, 0, 0);
      }
    }

    // soft-cap + causal mask + row max
    const bool diag = (t == nt - 1);
    float p[4][4], tmax[4];
#pragma unroll
    for (int r = 0; r < 4; ++r) tmax[r] = -1e30f;
#pragma unroll
    for (int n = 0; n < 4; ++n)
#pragma unroll
      for (int r = 0; r < 4; ++r) {
        float sv = 50.0f * fast_tanh(sacc[n][r] * (SCORE_SCALE / 50.0f));
        if (diag) {
          const int kg = kb + n * 16 + fr;
          const int qg = q0 + fq4 + r;
          if (kg > qg) sv = -1e9f;
        }
        p[n][r] = sv;
        tmax[r] = fmaxf(tmax[r], sv);
      }
#pragma unroll
    for (int r = 0; r < 4; ++r) {
      float v = tmax[r];
      v = fmaxf(v, __shfl_xor(v, 1));
      v = fmaxf(v, __shfl_xor(v, 2));
      v = fmaxf(v, __shfl_xor(v, 4));
      v = fmaxf(v, __shfl_xor(v, 8));
      tmax[r] = v;
    }
    float alpha[4], rsum[4];
#pragma unroll
    for (int r = 0; r < 4; ++r) {
      const float mnew = fmaxf(mrun[r], tmax[r]);
      alpha[r] = __expf(mrun[r] - mnew);
      mrun[r] = mnew;
      rsum[r] = 0.f;
    }
#pragma unroll
    for (int n = 0; n < 4; ++n)
#pragma unroll
      for (int r = 0; r < 4; ++r) {
        const float e = __expf(p[n][r] - mrun[r]);
        p[n][r] = e;
        rsum[r] += e;
      }
#pragma unroll
    for (int r = 0; r < 4; ++r) {
      float v = rsum[r];
      v += __shfl_xor(v, 1); v += __shfl_xor(v, 2);
      v += __shfl_xor(v, 4); v += __shfl_xor(v, 8);
      lrun[r] = lrun[r] * alpha[r] + v;
    }
#pragma unroll
    for (int n = 0; n < 8; ++n)
#pragma unroll
      for (int r = 0; r < 4; ++r) oacc[n][r] *= alpha[r];

    // P (C-layout) -> per-wave LDS (swizzled) -> A-fragment layout
    u16* ps = &Ps[wave][0];
#pragma unroll
    for (int n = 0; n < 4; ++n)
#pragma unroll
      for (int r = 0; r < 4; ++r) {
        const int prow = fq4 + r;
        const int chunk = n * 2 + (fr >> 3);
        ps[prow * 64 + ((chunk ^ (prow & 7)) << 3) + (fr & 7)] = f2bf(p[n][r]);
      }
    short8 pa[2];
#pragma unroll
    for (int kc = 0; kc < 2; ++kc)
      pa[kc] = *(const short8*)(ps + fr * 64 + (((kc * 4 + hi) ^ (fr & 7)) << 3));

    // O += P V   (swizzled V^T reads)
#pragma unroll
    for (int kc = 0; kc < 2; ++kc)
#pragma unroll
      for (int n = 0; n < 8; ++n) {
        const int row = n * 16 + fr;
        short8 b = *(const short8*)(&Vs[buf][row * 64 + (((kc * 4 + hi) ^ (fr & 7)) << 3)]);
        oacc[n] = __builtin_amdgcn_mfma_f32_16x16x32_bf16(pa[kc], b, oacc[n], 0, 0, 0);
      }
    __syncthreads();
  }

  // normalize + store [S][H*DH]
  float rl[4];
#pragma unroll
  for (int r = 0; r < 4; ++r) rl[r] = 1.0f / lrun[r];
#pragma unroll
  for (int n = 0; n < 8; ++n)
#pragma unroll
    for (int r = 0; r < 4; ++r) {
      const float v = oacc[n][r] * rl[r];
      ao[(size_t)(q0 + fq4 + r) * DD + h * DHD + n * 16 + fr] = f2bf(v);
    }
}

// ---------------- launch ----------------
extern "C" void kernel_launch(void* const* d_in, const int* in_sizes, int n_in,
                              void* d_out, int out_size, void* d_ws, size_t ws_size,
                              hipStream_t stream) {
  const float* x        = (const float*)d_in[0];
  const float* rope_cos = (const float*)d_in[1];
  const float* rope_sin = (const float*)d_in[2];
  // d_in[3] = mask: deterministic causal, handled inline
  const float* wq = (const float*)d_in[4];
  const float* wk = (const float*)d_in[5];
  const float* wv = (const float*)d_in[6];
  const float* wo = (const float*)d_in[7];
  float* out = (float*)d_out;

  // Workspace reuse plan (7 x 8MB = 56MB), sequential-stream safe.
  u16* ws = (u16*)d_ws;
  const size_t SZ = (size_t)SS * DD;
  u16* xb  = ws + 0 * SZ;
  u16* wqb = ws + 1 * SZ;             // -> reused as qt
  u16* wkb = ws + 2 * SZ;             // -> reused as kt
  u16* wvb = ws + 3 * SZ;             // -> reused as ao
  u16* q_  = ws + 4 * SZ;             // -> reused as wob
  u16* k_  = ws + 5 * SZ;
  u16* vt  = ws + 6 * SZ;
  u16* qt  = wqb;
  u16* kt  = wkb;
  u16* ao  = wvb;
  u16* wob = q_;

  const int cvtGrid = (int)(SZ / (256 * 8));
  cvt_bf16<<<cvtGrid, 256, 0, stream>>>(x,  xb);
  cvt_bf16<<<cvtGrid, 256, 0, stream>>>(wq, wqb);
  cvt_bf16<<<cvtGrid, 256, 0, stream>>>(wk, wkb);
  cvt_bf16<<<cvtGrid, 256, 0, stream>>>(wv, wvb);

  gemm_qkv<<<dim3(16, 16, 3), 256, 0, stream>>>(xb, wqb, wkb, wvb, q_, k_, vt);

  rope_qk<<<dim3(SS, HH), 128, 0, stream>>>(q_, k_, rope_cos, rope_sin, qt, kt);

  cvt_bf16<<<cvtGrid, 256, 0, stream>>>(wo, wob);  // q_ dead after rope

  attn_fwd<<<512, 256, 0, stream>>>(qt, kt, vt, ao);

  gemm_bt<float, false><<<dim3(16, 16), 256, 0, stream>>>(ao, wob, out);
}

// Round 5
// 320.725 us; speedup vs baseline: 1.4968x; 1.1324x over previous
//
#include <hip/hip_runtime.h>

// Problem constants (B=1)
#define SS 2048
#define DD 2048
#define HH 16
#define DHD 128

// scores scale: reference divides by sqrt(DH) with DH=128
#define SCORE_SCALE 0.08838834764831845f
// p = exp(50*tanh(u)-50) with u = s*SCORE_SCALE/50  ==>  p = exp(-100/(1+e^{2u}))
// C2 = 2*SCORE_SCALE/50  (so e^{2u} = __expf(s * C2))
#define C2 0.0035355339059327377f

typedef unsigned short u16;
typedef __attribute__((ext_vector_type(8))) short short8;
typedef __attribute__((ext_vector_type(4))) short short4v;
typedef __attribute__((ext_vector_type(4))) float f32x4;

__device__ __forceinline__ float bf2f(u16 v) {
  union { unsigned u; float f; } x; x.u = ((unsigned)v) << 16; return x.f;
}
__device__ __forceinline__ u16 f2bf(float f) {
  union { float f; unsigned u; } x; x.f = f;
  unsigned r = (x.u + 0x7fffu + ((x.u >> 16) & 1u)) >> 16;  // RTNE
  return (u16)r;
}

// async global->LDS, 16B per lane; LDS dest = wave-uniform base + lane*16
#define GL2LDS16(g, l) __builtin_amdgcn_global_load_lds( \
    (const __attribute__((address_space(1))) void*)(g),   \
    (__attribute__((address_space(3))) void*)(l), 16, 0, 0)

// ---------------- f32 -> bf16 convert (vectorized) ----------------
__global__ __launch_bounds__(256) void cvt_bf16(const float* __restrict__ in,
                                                u16* __restrict__ out) {
  int i = (blockIdx.x * 256 + threadIdx.x) * 8;
  float4 a = *(const float4*)(in + i);
  float4 b = *(const float4*)(in + i + 4);
  short8 o;
  o[0] = (short)f2bf(a.x); o[1] = (short)f2bf(a.y);
  o[2] = (short)f2bf(a.z); o[3] = (short)f2bf(a.w);
  o[4] = (short)f2bf(b.x); o[5] = (short)f2bf(b.y);
  o[6] = (short)f2bf(b.z); o[7] = (short)f2bf(b.w);
  *(short8*)(out + i) = o;
}

// ============ shared GEMM K-loop pieces (128x128 tile, BK=32, 2-phase) =======
// LDS tile swizzle: element (row, chunk c of 8 elems) stored at
//   row*32 + (c ^ (row&3))*8. Staging keeps LDS dest LINEAR (gl2lds req)
// and pre-swizzles the GLOBAL source chunk (both-sides-or-neither, m173).

#define GEMM_STAGE(Asrc, Bsrc, Adst, Bdst, kofs)                               \
  _Pragma("unroll")                                                            \
  for (int half = 0; half < 2; ++half) {                                       \
    const int rb = half * 64 + wave * 16;                                      \
    GL2LDS16(Asrc + (size_t)(bm + rb + lrow) * DD + (kofs) + c8s, Adst + rb * 32); \
    GL2LDS16(Bsrc + (size_t)(bn + rb + lrow) * DD + (kofs) + c8s, Bdst + rb * 32); \
  }

#define GEMM_COMPUTE(Abuf, Bbuf)                                               \
  {                                                                            \
    short8 af[4], bb[4];                                                       \
    _Pragma("unroll")                                                          \
    for (int m = 0; m < 4; ++m) {                                              \
      const int row = wm + m * 16 + fr;                                        \
      af[m] = *(const short8*)(Abuf + row * 32 + (hi ^ (row & 3)) * 8);        \
    }                                                                          \
    _Pragma("unroll")                                                          \
    for (int n = 0; n < 4; ++n) {                                              \
      const int row = wn + n * 16 + fr;                                        \
      bb[n] = *(const short8*)(Bbuf + row * 32 + (hi ^ (row & 3)) * 8);        \
    }                                                                          \
    __builtin_amdgcn_s_setprio(1);                                             \
    _Pragma("unroll")                                                          \
    for (int m = 0; m < 4; ++m)                                                \
      _Pragma("unroll")                                                        \
      for (int n = 0; n < 4; ++n)                                              \
        acc[m][n] = __builtin_amdgcn_mfma_f32_16x16x32_bf16(af[m], bb[n], acc[m][n], 0, 0, 0); \
    __builtin_amdgcn_s_setprio(0);                                             \
  }

// ---------------- GEMM: C[M][N] = A[M][K] * B[N][K]^T ------------------------
template<typename OUT, bool TR>
__global__ __launch_bounds__(256) void gemm_bt(const u16* __restrict__ A,
                                               const u16* __restrict__ B,
                                               OUT* __restrict__ C) {
  __shared__ u16 As[2][128 * 32];
  __shared__ u16 Bs[2][128 * 32];
  const int tid = threadIdx.x, wave = tid >> 6, lane = tid & 63;
  const int wm = (wave >> 1) * 64, wn = (wave & 1) * 64;
  const int bm = blockIdx.y * 128, bn = blockIdx.x * 128;
  const int lrow = lane >> 2;
  const int c8s = ((lane & 3) ^ (lrow & 3)) * 8;  // pre-swizzled global chunk
  const int fr = lane & 15, hi = lane >> 4, fq4 = hi * 4;
  f32x4 acc[4][4] = {};
  GEMM_STAGE(A, B, As[0], Bs[0], 0)
  __syncthreads();
  for (int kt = 0; kt < DD / 32; ++kt) {
    const int buf = kt & 1;
    if (kt + 1 < DD / 32) { GEMM_STAGE(A, B, As[buf ^ 1], Bs[buf ^ 1], (kt + 1) * 32) }
    GEMM_COMPUTE(As[buf], Bs[buf])
    __syncthreads();
  }
#pragma unroll
  for (int m = 0; m < 4; ++m)
#pragma unroll
    for (int n = 0; n < 4; ++n) {
      const int row0 = bm + wm + m * 16 + fq4;
      const int col  = bn + wn + n * 16 + fr;
      if constexpr (TR) {
        short4v t;
#pragma unroll
        for (int r = 0; r < 4; ++r) t[r] = (short)f2bf(acc[m][n][r]);
        *(short4v*)((u16*)C + (size_t)col * SS + row0) = t;
      } else {
#pragma unroll
        for (int r = 0; r < 4; ++r) {
          if constexpr (sizeof(OUT) == 2)
            ((u16*)C)[(size_t)(row0 + r) * DD + col] = f2bf(acc[m][n][r]);
          else
            ((float*)C)[(size_t)(row0 + r) * DD + col] = acc[m][n][r];
        }
      }
    }
}

// ---------------- z-batched QKV GEMM (z=0:Q, 1:K, 2:V-transposed) ------------
__global__ __launch_bounds__(256) void gemm_qkv(const u16* __restrict__ A,
                                                const u16* __restrict__ Bq,
                                                const u16* __restrict__ Bk,
                                                const u16* __restrict__ Bv,
                                                u16* __restrict__ Cq,
                                                u16* __restrict__ Ck,
                                                u16* __restrict__ Cvt) {
  __shared__ u16 As[2][128 * 32];
  __shared__ u16 Bs[2][128 * 32];
  const int z = blockIdx.z;
  const u16* B = (z == 0) ? Bq : (z == 1) ? Bk : Bv;
  const int tid = threadIdx.x, wave = tid >> 6, lane = tid & 63;
  const int wm = (wave >> 1) * 64, wn = (wave & 1) * 64;
  const int bm = blockIdx.y * 128, bn = blockIdx.x * 128;
  const int lrow = lane >> 2;
  const int c8s = ((lane & 3) ^ (lrow & 3)) * 8;
  const int fr = lane & 15, hi = lane >> 4, fq4 = hi * 4;
  f32x4 acc[4][4] = {};
  GEMM_STAGE(A, B, As[0], Bs[0], 0)
  __syncthreads();
  for (int kt = 0; kt < DD / 32; ++kt) {
    const int buf = kt & 1;
    if (kt + 1 < DD / 32) { GEMM_STAGE(A, B, As[buf ^ 1], Bs[buf ^ 1], (kt + 1) * 32) }
    GEMM_COMPUTE(As[buf], Bs[buf])
    __syncthreads();
  }
  u16* Cn = (z == 0) ? Cq : Ck;
#pragma unroll
  for (int m = 0; m < 4; ++m)
#pragma unroll
    for (int n = 0; n < 4; ++n) {
      const int row0 = bm + wm + m * 16 + fq4;
      const int col  = bn + wn + n * 16 + fr;
      if (z < 2) {
#pragma unroll
        for (int r = 0; r < 4; ++r)
          Cn[(size_t)(row0 + r) * DD + col] = f2bf(acc[m][n][r]);
      } else {
        short4v t;
#pragma unroll
        for (int r = 0; r < 4; ++r) t[r] = (short)f2bf(acc[m][n][r]);
        *(short4v*)(Cvt + (size_t)col * SS + row0) = t;
      }
    }
}

// ---------------- RoPE: q/k [S][H*DH] bf16 -> [H][S][DH] bf16 ----------------
__global__ __launch_bounds__(128) void rope_qk(const u16* __restrict__ qin,
                                               const u16* __restrict__ kin,
                                               const float* __restrict__ cosd,
                                               const float* __restrict__ sind,
                                               u16* __restrict__ qt,
                                               u16* __restrict__ kt) {
  const int s = blockIdx.x, h = blockIdx.y, d = threadIdx.x;
  const float c = cosd[s * DHD + d], sn = sind[s * DHD + d];
  const int base = s * DD + h * DHD;
  const float q0 = bf2f(qin[base + d]);
  const float k0 = bf2f(kin[base + d]);
  const float qr = (d < 64) ? -bf2f(qin[base + d + 64]) : bf2f(qin[base + d - 64]);
  const float kr = (d < 64) ? -bf2f(kin[base + d + 64]) : bf2f(kin[base + d - 64]);
  const size_t o = ((size_t)h * SS + s) * DHD + d;
  qt[o] = f2bf(q0 * c + qr * sn);
  kt[o] = f2bf(k0 * c + kr * sn);
}

// ---------------- Flash attention (causal, tanh soft-cap 50) -----------------
// 1-D grid 512 blocks. h = (bid&7)+8*((bid>>3)&1): each XCD keeps 2 heads' K/V
// in its L2. qb = 31-(bid>>4): LONGEST q-blocks dispatch first (LPT schedule;
// earliest-free CU picks next-longest remainder -> per-CU total ~33 tiles).
// FIXED-max softmax: tanh cap bounds s<=50, so m=50 always:
//   p = exp(s-50) = exp(-100/(1+e^{2u})) -- no online max/rescale at all.
__global__ __launch_bounds__(256) void attn_fwd(const u16* __restrict__ qt,
                                                const u16* __restrict__ kt,
                                                const u16* __restrict__ vt,
                                                u16* __restrict__ ao) {
  __shared__ u16 Ks[2][64 * 128];
  __shared__ u16 Vs[2][128 * 64];
  __shared__ u16 Ps[4][16 * 64];
  const int bid = blockIdx.x;
  const int h  = (bid & 7) + 8 * ((bid >> 3) & 1);
  const int qb = (SS / 64 - 1) - (bid >> 4);
  const int tid = threadIdx.x, wave = tid >> 6, lane = tid & 63;
  const int q0 = qb * 64 + wave * 16;
  const int fr = lane & 15, hi = lane >> 4, fq8 = hi * 8, fq4 = hi * 4;

  // staging address components
  const int kbrow0 = wave * 4 + (lane >> 4);      // + i*16 -> K row
  const int kc8    = (lane & 15);
  const int vbrow0 = wave * 8 + (lane >> 3);      // + i*32 -> V^T row
  const int vk8    = (lane & 7) ^ ((lane >> 3) & 7);

  short8 qf[4];
#pragma unroll
  for (int c = 0; c < 4; ++c)
    qf[c] = *(const short8*)(qt + ((size_t)h * SS + q0 + fr) * DHD + c * 32 + fq8);

  f32x4 oacc[8] = {};
  float lsum[4] = {0.f, 0.f, 0.f, 0.f};

  const int nt = qb + 1;

  auto STAGE = [&](int t, int buf) {
    const int kb = t * 64;
#pragma unroll
    for (int i = 0; i < 4; ++i) {
      const int krow = i * 16 + kbrow0;
      const int c8 = kc8 ^ (krow & 7);
      GL2LDS16(kt + ((size_t)h * SS + kb + krow) * DHD + c8 * 8,
               &Ks[buf][(i * 16 + wave * 4) * 128]);
    }
#pragma unroll
    for (int i = 0; i < 4; ++i) {
      const int vrow = i * 32 + vbrow0;
      GL2LDS16(vt + ((size_t)h * DHD + vrow) * SS + kb + vk8 * 8,
               &Vs[buf][(i * 32 + wave * 8) * 64]);
    }
  };

  STAGE(0, 0);
  __syncthreads();

  for (int t = 0; t < nt; ++t) {
    const int buf = t & 1;
    if (t + 1 < nt) STAGE(t + 1, buf ^ 1);
    const int kb = t * 64;

    // S = Q K^T  (swizzled K reads)
    f32x4 sacc[4] = {};
    __builtin_amdgcn_s_setprio(1);
#pragma unroll
    for (int n = 0; n < 4; ++n) {
      const int row = n * 16 + fr;
#pragma unroll
      for (int c = 0; c < 4; ++c) {
        short8 b = *(const short8*)(&Ks[buf][row * 128 + ((c * 4 + hi) ^ (fr & 7)) * 8]);
        sacc[n] = __builtin_amdgcn_mfma_f32_16x16x32_bf16(qf[c], b, sacc[n], 0, 0, 0);
      }
    }
    __builtin_amdgcn_s_setprio(0);

    // fixed-max softcap softmax: p = exp(-100/(1+e^{2u})), masked -> 0
    const bool diag = (t == nt - 1);
    float p[4][4];
#pragma unroll
    for (int n = 0; n < 4; ++n)
#pragma unroll
      for (int r = 0; r < 4; ++r) {
        const float w = __expf(sacc[n][r] * C2);
        float pv = __expf(-100.0f * __builtin_amdgcn_rcpf(1.0f + w));
        if (diag) {
          const int kg = kb + n * 16 + fr;
          if (kg > q0 + fq4 + r) pv = 0.0f;
        }
        p[n][r] = pv;
        lsum[r] += pv;
      }

    // P (C-layout) -> per-wave LDS (swizzled) -> A-fragment layout
    u16* ps = &Ps[wave][0];
#pragma unroll
    for (int n = 0; n < 4; ++n)
#pragma unroll
      for (int r = 0; r < 4; ++r) {
        const int prow = fq4 + r;
        const int chunk = n * 2 + (fr >> 3);
        ps[prow * 64 + ((chunk ^ (prow & 7)) << 3) + (fr & 7)] = f2bf(p[n][r]);
      }
    short8 pa[2];
#pragma unroll
    for (int kc = 0; kc < 2; ++kc)
      pa[kc] = *(const short8*)(ps + fr * 64 + (((kc * 4 + hi) ^ (fr & 7)) << 3));

    // O += P V   (swizzled V^T reads)
    __builtin_amdgcn_s_setprio(1);
#pragma unroll
    for (int kc = 0; kc < 2; ++kc)
#pragma unroll
      for (int n = 0; n < 8; ++n) {
        const int row = n * 16 + fr;
        short8 b = *(const short8*)(&Vs[buf][row * 64 + (((kc * 4 + hi) ^ (fr & 7)) << 3)]);
        oacc[n] = __builtin_amdgcn_mfma_f32_16x16x32_bf16(pa[kc], b, oacc[n], 0, 0, 0);
      }
    __builtin_amdgcn_s_setprio(0);
    __syncthreads();
  }

  // row-sum reduce (deferred out of the loop), normalize + store [S][H*DH]
  float rl[4];
#pragma unroll
  for (int r = 0; r < 4; ++r) {
    float v = lsum[r];
    v += __shfl_xor(v, 1); v += __shfl_xor(v, 2);
    v += __shfl_xor(v, 4); v += __shfl_xor(v, 8);
    rl[r] = 1.0f / v;
  }
#pragma unroll
  for (int n = 0; n < 8; ++n)
#pragma unroll
    for (int r = 0; r < 4; ++r) {
      const float v = oacc[n][r] * rl[r];
      ao[(size_t)(q0 + fq4 + r) * DD + h * DHD + n * 16 + fr] = f2bf(v);
    }
}

// ---------------- launch ----------------
extern "C" void kernel_launch(void* const* d_in, const int* in_sizes, int n_in,
                              void* d_out, int out_size, void* d_ws, size_t ws_size,
                              hipStream_t stream) {
  const float* x        = (const float*)d_in[0];
  const float* rope_cos = (const float*)d_in[1];
  const float* rope_sin = (const float*)d_in[2];
  // d_in[3] = mask: deterministic causal, handled inline
  const float* wq = (const float*)d_in[4];
  const float* wk = (const float*)d_in[5];
  const float* wv = (const float*)d_in[6];
  const float* wo = (const float*)d_in[7];
  float* out = (float*)d_out;

  // Workspace reuse plan (7 x 8MB = 56MB), sequential-stream safe.
  u16* ws = (u16*)d_ws;
  const size_t SZ = (size_t)SS * DD;
  u16* xb  = ws + 0 * SZ;
  u16* wqb = ws + 1 * SZ;             // -> reused as qt
  u16* wkb = ws + 2 * SZ;             // -> reused as kt
  u16* wvb = ws + 3 * SZ;             // -> reused as ao
  u16* q_  = ws + 4 * SZ;             // -> reused as wob
  u16* k_  = ws + 5 * SZ;
  u16* vt  = ws + 6 * SZ;
  u16* qt  = wqb;
  u16* kt  = wkb;
  u16* ao  = wvb;
  u16* wob = q_;

  const int cvtGrid = (int)(SZ / (256 * 8));
  cvt_bf16<<<cvtGrid, 256, 0, stream>>>(x,  xb);
  cvt_bf16<<<cvtGrid, 256, 0, stream>>>(wq, wqb);
  cvt_bf16<<<cvtGrid, 256, 0, stream>>>(wk, wkb);
  cvt_bf16<<<cvtGrid, 256, 0, stream>>>(wv, wvb);

  gemm_qkv<<<dim3(16, 16, 3), 256, 0, stream>>>(xb, wqb, wkb, wvb, q_, k_, vt);

  rope_qk<<<dim3(SS, HH), 128, 0, stream>>>(q_, k_, rope_cos, rope_sin, qt, kt);

  cvt_bf16<<<cvtGrid, 256, 0, stream>>>(wo, wob);  // q_ dead after rope

  attn_fwd<<<512, 256, 0, stream>>>(qt, kt, vt, ao);

  gemm_bt<float, false><<<dim3(16, 16), 256, 0, stream>>>(ao, wob, out);
}